// Round 7
// baseline (32.776 us; speedup 1.0000x reference)
//
#include <hip/hip_runtime.h>
#include <math.h>

#define BSZ   65536
#define INP   16
#define HL    10
#define NL    3
#define TT    200
#define NPOP  8600000.0f

#define NCH16 12   // 12 chunks of 16 steps + tail of 7 = 199

__device__ __forceinline__ float fast_tanh(float x) {
    float e = exp2f(x * 2.8853900817779268f);
    return 1.0f - 2.0f * __builtin_amdgcn_rcpf(e + 1.0f);
}

// ---------------- Kernel A: parameter nets, one thread per (sample, net) ----
__global__ __launch_bounds__(256) void mlp_kernel(
    const float* __restrict__ data,   // B x IN
    const float* __restrict__ W0,     // 3 x HL x IN
    const float* __restrict__ b0,     // 3 x HL
    const float* __restrict__ Wh,     // 3 x NL x HL x HL
    const float* __restrict__ bh,     // 3 x NL x HL
    const float* __restrict__ Wo,     // 3 x 1 x HL
    const float* __restrict__ bo,     // 3 x 1
    float* __restrict__ vals)         // 3 x B
{
    const int n   = blockIdx.y;
    const int tid = threadIdx.x;

    __shared__ float sW0[HL * INP];
    __shared__ float sb0[HL];
    __shared__ float sWh[NL * HL * HL];
    __shared__ float sbh[NL * HL];
    __shared__ float sWo[HL];
    __shared__ float sbo;

    for (int i = tid; i < HL * INP;      i += 256) sW0[i] = W0[n * HL * INP + i];
    for (int i = tid; i < HL;            i += 256) sb0[i] = b0[n * HL + i];
    for (int i = tid; i < NL * HL * HL;  i += 256) sWh[i] = Wh[n * NL * HL * HL + i];
    for (int i = tid; i < NL * HL;       i += 256) sbh[i] = bh[n * NL * HL + i];
    for (int i = tid; i < HL;            i += 256) sWo[i] = Wo[n * HL + i];
    if (tid == 0) sbo = bo[n];
    __syncthreads();

    const int b = blockIdx.x * 256 + tid;

    float x[INP];
    const float4* xin = reinterpret_cast<const float4*>(data + (size_t)b * INP);
    #pragma unroll
    for (int q = 0; q < INP / 4; ++q) {
        float4 v = xin[q];
        x[q * 4 + 0] = v.x; x[q * 4 + 1] = v.y;
        x[q * 4 + 2] = v.z; x[q * 4 + 3] = v.w;
    }

    float h[HL];
    #pragma unroll
    for (int k = 0; k < HL; ++k) {
        float acc = sb0[k];
        #pragma unroll
        for (int i = 0; i < INP; ++i)
            acc = fmaf(x[i], sW0[k * INP + i], acc);
        h[k] = fast_tanh(acc);
    }
    #pragma unroll
    for (int l = 0; l < NL; ++l) {
        float h2[HL];
        #pragma unroll
        for (int k = 0; k < HL; ++k) {
            float acc = sbh[l * HL + k];
            #pragma unroll
            for (int i = 0; i < HL; ++i)
                acc = fmaf(h[i], sWh[(l * HL + k) * HL + i], acc);
            h2[k] = fast_tanh(acc);
        }
        #pragma unroll
        for (int k = 0; k < HL; ++k) h[k] = h2[k];
    }
    float acc = sbo;
    #pragma unroll
    for (int i = 0; i < HL; ++i)
        acc = fmaf(h[i], sWo[i], acc);

    vals[(size_t)n * BSZ + b] = fmaxf(acc, 0.0f) + log1pf(expf(-fabsf(acc)));
}

// ---------------- Kernel B: RK4 integration, one thread per sample ----------
__global__ __launch_bounds__(256, 1) void sir_kernel(
    const float* __restrict__ vals,   // 3 x B
    const float* __restrict__ times,  // T
    float* __restrict__ out)          // T x B
{
    const int tid = threadIdx.x;
    const int b = blockIdx.x * 256 + tid;

    const float gamma = vals[b];
    const float beta  = vals[BSZ + b];
    const float I0    = vals[2 * BSZ + b];

    __shared__ float sdt[208];        // 52 float4s, zero-padded past 198
    if (tid < TT - 1)       sdt[tid] = times[tid + 1] - times[tid];
    else if (tid < 208)     sdt[tid] = 0.0f;
    __syncthreads();

    float S = NPOP - I0;
    float I = I0;
    const float bn = beta * (1.0f / NPOP);

    out[b] = I;   // t = 0

    // folded RK4 step: negations absorbed into fma coefficients
    auto step = [&](float dt) {
        const float hdt = 0.5f * dt;
        float f1 = (bn * S) * I;
        float r1 = gamma * I;
        float m1 = f1 - r1;
        float aS = fmaf(-hdt, f1, S), aI = fmaf(hdt, m1, I);
        float f2 = (bn * aS) * aI;
        float r2 = gamma * aI;
        float m2 = f2 - r2;
        float bS = fmaf(-hdt, f2, S), bI = fmaf(hdt, m2, I);
        float f3 = (bn * bS) * bI;
        float r3 = gamma * bI;
        float m3 = f3 - r3;
        float cS = fmaf(-dt, f3, S),  cI = fmaf(dt, m3, I);
        float f4 = (bn * cS) * cI;
        float r4 = gamma * cI;
        float m4 = f4 - r4;
        const float c6 = dt * (1.0f / 6.0f);
        S = fmaf(-c6, (f1 + f4) + 2.0f * (f2 + f3), S);
        I = fmaf( c6, (m1 + m4) + 2.0f * (m2 + m3), I);
    };

    const float4* sdt4 = reinterpret_cast<const float4*>(sdt);

    float4 da = sdt4[0];
    float4 db = sdt4[1];
    float4 dc = sdt4[2];
    float4 dd = sdt4[3];
    float* op = out + BSZ;            // row t = 1

    #pragma unroll 1
    for (int g = 0; g < NCH16; ++g) {
        // prefetch next chunk's 16 dts
        float4 na = sdt4[4 * g + 4];
        float4 nb = sdt4[4 * g + 5];
        float4 nc = sdt4[4 * g + 6];
        float4 nd = sdt4[4 * g + 7];
        __builtin_amdgcn_sched_barrier(0);   // pin prefetch above the step block

        float ic0, ic1, ic2, ic3, ic4, ic5, ic6, ic7;
        float ic8, ic9, ic10, ic11, ic12, ic13, ic14, ic15;
        step(da.x); ic0  = I; op[b           ] = ic0;
        step(da.y); ic1  = I; op[b +  1 * BSZ] = ic1;
        step(da.z); ic2  = I; op[b +  2 * BSZ] = ic2;
        step(da.w); ic3  = I; op[b +  3 * BSZ] = ic3;
        step(db.x); ic4  = I; op[b +  4 * BSZ] = ic4;
        step(db.y); ic5  = I; op[b +  5 * BSZ] = ic5;
        step(db.z); ic6  = I; op[b +  6 * BSZ] = ic6;
        step(db.w); ic7  = I; op[b +  7 * BSZ] = ic7;
        step(dc.x); ic8  = I; op[b +  8 * BSZ] = ic8;
        step(dc.y); ic9  = I; op[b +  9 * BSZ] = ic9;
        step(dc.z); ic10 = I; op[b + 10 * BSZ] = ic10;
        step(dc.w); ic11 = I; op[b + 11 * BSZ] = ic11;
        step(dd.x); ic12 = I; op[b + 12 * BSZ] = ic12;
        step(dd.y); ic13 = I; op[b + 13 * BSZ] = ic13;
        step(dd.z); ic14 = I; op[b + 14 * BSZ] = ic14;
        step(dd.w); ic15 = I; op[b + 15 * BSZ] = ic15;

        // 16 distinct live store-data regs -> reuse distance 15 steps (~1.1k cy)
        asm volatile("" :: "v"(ic0),  "v"(ic1),  "v"(ic2),  "v"(ic3),
                           "v"(ic4),  "v"(ic5),  "v"(ic6),  "v"(ic7),
                           "v"(ic8),  "v"(ic9),  "v"(ic10), "v"(ic11),
                           "v"(ic12), "v"(ic13), "v"(ic14), "v"(ic15));

        da = na; db = nb; dc = nc; dd = nd;
        op += 16 * BSZ;
    }

    // tail: 7 steps (t = 192..198)
    {
        float d0 = sdt[192], d1 = sdt[193], d2 = sdt[194], d3 = sdt[195];
        float d4 = sdt[196], d5 = sdt[197], d6 = sdt[198];
        float ic0, ic1, ic2, ic3, ic4, ic5, ic6;
        step(d0); ic0 = I; op[b          ] = ic0;
        step(d1); ic1 = I; op[b + 1 * BSZ] = ic1;
        step(d2); ic2 = I; op[b + 2 * BSZ] = ic2;
        step(d3); ic3 = I; op[b + 3 * BSZ] = ic3;
        step(d4); ic4 = I; op[b + 4 * BSZ] = ic4;
        step(d5); ic5 = I; op[b + 5 * BSZ] = ic5;
        step(d6); ic6 = I; op[b + 6 * BSZ] = ic6;
        asm volatile("" :: "v"(ic0), "v"(ic1), "v"(ic2), "v"(ic3),
                           "v"(ic4), "v"(ic5), "v"(ic6));
    }
}

extern "C" void kernel_launch(void* const* d_in, const int* in_sizes, int n_in,
                              void* d_out, int out_size, void* d_ws, size_t ws_size,
                              hipStream_t stream) {
    const float* data  = (const float*)d_in[0];
    const float* times = (const float*)d_in[1];
    const float* W0    = (const float*)d_in[2];
    const float* b0    = (const float*)d_in[3];
    const float* Wh    = (const float*)d_in[4];
    const float* bh    = (const float*)d_in[5];
    const float* Wo    = (const float*)d_in[6];
    const float* bo    = (const float*)d_in[7];
    float* out  = (float*)d_out;
    float* vals = (float*)d_ws;       // 3 * BSZ floats = 768 KB

    dim3 gridA(BSZ / 256, 3);
    mlp_kernel<<<gridA, 256, 0, stream>>>(data, W0, b0, Wh, bh, Wo, bo, vals);
    sir_kernel<<<BSZ / 256, 256, 0, stream>>>(vals, times, out);
}

// Round 8
// 31.933 us; speedup vs baseline: 1.0264x; 1.0264x over previous
//
#include <hip/hip_runtime.h>
#include <math.h>

#define BSZ   65536
#define INP   16
#define HL    10
#define NL    3
#define TT    200
#define NPOP  8600000.0f
#define ROWB  (BSZ * 4u)     // bytes per t-row of out

__device__ __forceinline__ float fast_tanh(float x) {
    float e = exp2f(x * 2.8853900817779268f);
    return 1.0f - 2.0f * __builtin_amdgcn_rcpf(e + 1.0f);
}

// ---------------- Kernel A: parameter nets, one thread per (sample, net) ----
__global__ __launch_bounds__(256) void mlp_kernel(
    const float* __restrict__ data,
    const float* __restrict__ W0,  const float* __restrict__ b0,
    const float* __restrict__ Wh,  const float* __restrict__ bh,
    const float* __restrict__ Wo,  const float* __restrict__ bo,
    float* __restrict__ vals)         // 3 x B
{
    const int n   = blockIdx.y;
    const int tid = threadIdx.x;

    __shared__ float sW0[HL * INP];
    __shared__ float sb0[HL];
    __shared__ float sWh[NL * HL * HL];
    __shared__ float sbh[NL * HL];
    __shared__ float sWo[HL];
    __shared__ float sbo;

    for (int i = tid; i < HL * INP;      i += 256) sW0[i] = W0[n * HL * INP + i];
    for (int i = tid; i < HL;            i += 256) sb0[i] = b0[n * HL + i];
    for (int i = tid; i < NL * HL * HL;  i += 256) sWh[i] = Wh[n * NL * HL * HL + i];
    for (int i = tid; i < NL * HL;       i += 256) sbh[i] = bh[n * NL * HL + i];
    for (int i = tid; i < HL;            i += 256) sWo[i] = Wo[n * HL + i];
    if (tid == 0) sbo = bo[n];
    __syncthreads();

    const int b = blockIdx.x * 256 + tid;

    float x[INP];
    const float4* xin = reinterpret_cast<const float4*>(data + (size_t)b * INP);
    #pragma unroll
    for (int q = 0; q < INP / 4; ++q) {
        float4 v = xin[q];
        x[q * 4 + 0] = v.x; x[q * 4 + 1] = v.y;
        x[q * 4 + 2] = v.z; x[q * 4 + 3] = v.w;
    }

    float h[HL];
    #pragma unroll
    for (int k = 0; k < HL; ++k) {
        float acc = sb0[k];
        #pragma unroll
        for (int i = 0; i < INP; ++i)
            acc = fmaf(x[i], sW0[k * INP + i], acc);
        h[k] = fast_tanh(acc);
    }
    #pragma unroll
    for (int l = 0; l < NL; ++l) {
        float h2[HL];
        #pragma unroll
        for (int k = 0; k < HL; ++k) {
            float acc = sbh[l * HL + k];
            #pragma unroll
            for (int i = 0; i < HL; ++i)
                acc = fmaf(h[i], sWh[(l * HL + k) * HL + i], acc);
            h2[k] = fast_tanh(acc);
        }
        #pragma unroll
        for (int k = 0; k < HL; ++k) h[k] = h2[k];
    }
    float acc = sbo;
    #pragma unroll
    for (int i = 0; i < HL; ++i)
        acc = fmaf(h[i], sWo[i], acc);

    vals[(size_t)n * BSZ + b] = fmaxf(acc, 0.0f) + log1pf(expf(-fabsf(acc)));
}

// ---------------- Kernel B: RK4 integration, inline-asm store path ----------
#define ST(VOFF, VAL) \
    asm volatile("global_store_dword %0, %1, %2" \
                 :: "v"(VOFF), "v"(VAL), "s"(out) : "memory")

#define KEEP16(A) \
    asm volatile("" :: "v"(A[0]),  "v"(A[1]),  "v"(A[2]),  "v"(A[3]),  \
                       "v"(A[4]),  "v"(A[5]),  "v"(A[6]),  "v"(A[7]),  \
                       "v"(A[8]),  "v"(A[9]),  "v"(A[10]), "v"(A[11]), \
                       "v"(A[12]), "v"(A[13]), "v"(A[14]), "v"(A[15]))

__global__ __launch_bounds__(256, 1) void sir_kernel(
    const float* __restrict__ vals,   // 3 x B
    const float* __restrict__ times,  // T
    float* __restrict__ out)          // T x B
{
    const int tid = threadIdx.x;
    const int b = blockIdx.x * 256 + tid;

    const float gamma = vals[b];
    const float beta  = vals[BSZ + b];
    const float I0    = vals[2 * BSZ + b];

    __shared__ float sdt[208];        // 52 float4s, zero-padded past 198
    if (tid < TT - 1)       sdt[tid] = times[tid + 1] - times[tid];
    else if (tid < 208)     sdt[tid] = 0.0f;
    __syncthreads();

    float S = NPOP - I0;
    float I = I0;
    const float bn = beta * (1.0f / NPOP);

    out[b] = I;   // t = 0 (plain store, pre-loop)

    auto step = [&](float dt) {
        const float hdt = 0.5f * dt;
        float f1 = (bn * S) * I;
        float r1 = gamma * I;
        float m1 = f1 - r1;
        float aS = fmaf(-hdt, f1, S), aI = fmaf(hdt, m1, I);
        float f2 = (bn * aS) * aI;
        float r2 = gamma * aI;
        float m2 = f2 - r2;
        float bS = fmaf(-hdt, f2, S), bI = fmaf(hdt, m2, I);
        float f3 = (bn * bS) * bI;
        float r3 = gamma * bI;
        float m3 = f3 - r3;
        float cS = fmaf(-dt, f3, S),  cI = fmaf(dt, m3, I);
        float f4 = (bn * cS) * cI;
        float r4 = gamma * cI;
        float m4 = f4 - r4;
        const float c6 = dt * (1.0f / 6.0f);
        S = fmaf(-c6, (f1 + f4) + 2.0f * (f2 + f3), S);
        I = fmaf( c6, (m1 + m4) + 2.0f * (m2 + m3), I);
    };

    const float4* sdt4 = reinterpret_cast<const float4*>(sdt);

    // persistent per-row store offsets (bytes), ping-pong A/B sets.
    // Set X covers rows (first-use) and advances by +32 rows each use;
    // init = first-use rows - 32 (uint wrap is transient only).
    const unsigned vb = (unsigned)b * 4u;
    unsigned voffA[16], voffB[16];
    #pragma unroll
    for (int k = 0; k < 16; ++k) {
        voffA[k] = (unsigned)(k + 1  - 32) * ROWB + vb;
        voffB[k] = (unsigned)(k + 17 - 32) * ROWB + vb;
    }
    float icA[16], icB[16];
    #pragma unroll
    for (int k = 0; k < 16; ++k) { icA[k] = 0.0f; icB[k] = 0.0f; }

    float4 d0 = sdt4[0], d1 = sdt4[1], d2 = sdt4[2], d3 = sdt4[3];
    float4 e0, e1, e2, e3;

    #pragma unroll 1
    for (int j = 0; j < 6; ++j) {
        // ---------- A half: steps 32j .. 32j+15 -> rows 32j+1 .. 32j+16 ----
        // in-order vmcnt: <=16 outstanding => all but newest 16 (= B half j-1)
        // complete => A set (j-1) operands read -> safe to overwrite.
        asm volatile("s_waitcnt vmcnt(16)" ::: "memory");
        KEEP16(icA);                          // pin A-set liveness to this point
        __builtin_amdgcn_sched_barrier(0);
        #pragma unroll
        for (int k = 0; k < 16; ++k) voffA[k] += 32u * ROWB;
        e0 = sdt4[8 * j + 4]; e1 = sdt4[8 * j + 5];
        e2 = sdt4[8 * j + 6]; e3 = sdt4[8 * j + 7];
        __builtin_amdgcn_sched_barrier(0);

        step(d0.x); icA[0]  = I; ST(voffA[0],  icA[0]);
        step(d0.y); icA[1]  = I; ST(voffA[1],  icA[1]);
        step(d0.z); icA[2]  = I; ST(voffA[2],  icA[2]);
        step(d0.w); icA[3]  = I; ST(voffA[3],  icA[3]);
        step(d1.x); icA[4]  = I; ST(voffA[4],  icA[4]);
        step(d1.y); icA[5]  = I; ST(voffA[5],  icA[5]);
        step(d1.z); icA[6]  = I; ST(voffA[6],  icA[6]);
        step(d1.w); icA[7]  = I; ST(voffA[7],  icA[7]);
        step(d2.x); icA[8]  = I; ST(voffA[8],  icA[8]);
        step(d2.y); icA[9]  = I; ST(voffA[9],  icA[9]);
        step(d2.z); icA[10] = I; ST(voffA[10], icA[10]);
        step(d2.w); icA[11] = I; ST(voffA[11], icA[11]);
        step(d3.x); icA[12] = I; ST(voffA[12], icA[12]);
        step(d3.y); icA[13] = I; ST(voffA[13], icA[13]);
        step(d3.z); icA[14] = I; ST(voffA[14], icA[14]);
        step(d3.w); icA[15] = I; ST(voffA[15], icA[15]);

        // ---------- B half: steps 32j+16 .. 32j+31 -> rows 32j+17 .. 32j+32 -
        asm volatile("s_waitcnt vmcnt(16)" ::: "memory");
        KEEP16(icB);
        __builtin_amdgcn_sched_barrier(0);
        #pragma unroll
        for (int k = 0; k < 16; ++k) voffB[k] += 32u * ROWB;
        d0 = sdt4[8 * j + 8];  d1 = sdt4[8 * j + 9];
        d2 = sdt4[8 * j + 10]; d3 = sdt4[8 * j + 11];
        __builtin_amdgcn_sched_barrier(0);

        step(e0.x); icB[0]  = I; ST(voffB[0],  icB[0]);
        step(e0.y); icB[1]  = I; ST(voffB[1],  icB[1]);
        step(e0.z); icB[2]  = I; ST(voffB[2],  icB[2]);
        step(e0.w); icB[3]  = I; ST(voffB[3],  icB[3]);
        step(e1.x); icB[4]  = I; ST(voffB[4],  icB[4]);
        step(e1.y); icB[5]  = I; ST(voffB[5],  icB[5]);
        step(e1.z); icB[6]  = I; ST(voffB[6],  icB[6]);
        step(e1.w); icB[7]  = I; ST(voffB[7],  icB[7]);
        step(e2.x); icB[8]  = I; ST(voffB[8],  icB[8]);
        step(e2.y); icB[9]  = I; ST(voffB[9],  icB[9]);
        step(e2.z); icB[10] = I; ST(voffB[10], icB[10]);
        step(e2.w); icB[11] = I; ST(voffB[11], icB[11]);
        step(e3.x); icB[12] = I; ST(voffB[12], icB[12]);
        step(e3.y); icB[13] = I; ST(voffB[13], icB[13]);
        step(e3.z); icB[14] = I; ST(voffB[14], icB[14]);
        step(e3.w); icB[15] = I; ST(voffB[15], icB[15]);
    }
    // after loop: d0..d3 = sdt[192..207] (zero-padded)

    // ---------- tail: steps 192..198 -> rows 193..199 ----------
    asm volatile("s_waitcnt vmcnt(0)" ::: "memory");
    KEEP16(icA);
    KEEP16(icB);
    __builtin_amdgcn_sched_barrier(0);
    #pragma unroll
    for (int k = 0; k < 7; ++k) voffA[k] += 32u * ROWB;   // rows 193..199

    step(d0.x); icA[0] = I; ST(voffA[0], icA[0]);
    step(d0.y); icA[1] = I; ST(voffA[1], icA[1]);
    step(d0.z); icA[2] = I; ST(voffA[2], icA[2]);
    step(d0.w); icA[3] = I; ST(voffA[3], icA[3]);
    step(d1.x); icA[4] = I; ST(voffA[4], icA[4]);
    step(d1.y); icA[5] = I; ST(voffA[5], icA[5]);
    step(d1.z); icA[6] = I; ST(voffA[6], icA[6]);
}

extern "C" void kernel_launch(void* const* d_in, const int* in_sizes, int n_in,
                              void* d_out, int out_size, void* d_ws, size_t ws_size,
                              hipStream_t stream) {
    const float* data  = (const float*)d_in[0];
    const float* times = (const float*)d_in[1];
    const float* W0    = (const float*)d_in[2];
    const float* b0    = (const float*)d_in[3];
    const float* Wh    = (const float*)d_in[4];
    const float* bh    = (const float*)d_in[5];
    const float* Wo    = (const float*)d_in[6];
    const float* bo    = (const float*)d_in[7];
    float* out  = (float*)d_out;
    float* vals = (float*)d_ws;       // 3 * BSZ floats = 768 KB

    dim3 gridA(BSZ / 256, 3);
    mlp_kernel<<<gridA, 256, 0, stream>>>(data, W0, b0, Wh, bh, Wo, bo, vals);
    sir_kernel<<<BSZ / 256, 256, 0, stream>>>(vals, times, out);
}